// Round 1
// baseline (289.521 us; speedup 1.0000x reference)
//
#include <hip/hip_runtime.h>
#include <hip/hip_bf16.h>
#include <cstdint>
#include <cstddef>

// LinearAttention fused pipeline for MI355X (gfx950).
//   x:(8,256,16384) f32, w_qkv:(768,256), w_out:(256,256), b_out:(256), gn_w/gn_b:(256)
// Pipeline:
//   k_init : w_qkv -> bf16, zero accumulators
//   k_qkv  : qkv = w_qkv@x (MFMA bf16), q-softmax(d)*SCALE -> q_ws (bf16),
//            ek=exp(k) ; ctx[b,h,d,e] += ek@v^T ; Z[b,c] += row-sums (atomics)
//   k_w2   : W2[b,o,hd] = sum_e w_out[o,he]*ctx[b,h,d,e]/Z[b,hd]  (bf16)
//   k_out  : y = W2_b @ q_b + b_out -> d_out (f32), per-batch sum/sumsq atomics
//   k_stats: mean/var -> scale/shift
//   k_norm : d_out = d_out*A[b,c] + B[b,c] in place (GroupNorm + gn_w/gn_b)

#define NB 8
#define NC 256
#define NL 16384
#define NH 8
#define ND 32
#define NO3 768

#define Q_SCALE 0.17677669529663687f
#define GN_EPS 1e-5f

using f32x4  = __attribute__((ext_vector_type(4))) float;
using bf16x8 = __attribute__((ext_vector_type(8))) __bf16;
using u32x4  = __attribute__((ext_vector_type(4))) unsigned int;

__device__ __forceinline__ float bf2f(unsigned short u) {
    union { unsigned int i; float f; } v; v.i = ((unsigned int)u) << 16; return v.f;
}
__device__ __forceinline__ unsigned short f2bf(float f) {
    union { float f; unsigned int i; } v; v.f = f;
    v.i += 0x7fffu + ((v.i >> 16) & 1u);   // RNE
    return (unsigned short)(v.i >> 16);
}
__device__ __forceinline__ bf16x8 ldfrag(const unsigned short* p) {
    return __builtin_bit_cast(bf16x8, *(const u32x4*)p);
}

// ---------------------------------------------------------------- init
__global__ __launch_bounds__(256) void k_init(
    const float* __restrict__ wqkv, unsigned short* __restrict__ wq,
    float* __restrict__ ctx, float* __restrict__ Zs, float* __restrict__ stats)
{
    const int i0 = blockIdx.x * 256 + threadIdx.x;
    const int stride = gridDim.x * 256;
    for (int i = i0; i < NO3 * NC; i += stride) wq[i] = f2bf(wqkv[i]);
    for (int i = i0; i < NB * NH * ND * ND; i += stride) ctx[i] = 0.f;
    for (int i = i0; i < NB * NC; i += stride) Zs[i] = 0.f;
    if (i0 < 16) stats[i0] = 0.f;
}

// ---------------------------------------------------------------- pass 1
// grid (NL/64, NB), 512 threads (8 waves). Per block: 768x64 qkv tile.
__global__ __launch_bounds__(512) void k_qkv(
    const float* __restrict__ x, const unsigned short* __restrict__ wq,
    unsigned short* __restrict__ q_ws, float* __restrict__ ctx, float* __restrict__ Zs)
{
    __shared__ __align__(16) unsigned short xT[64 * 256];   // [l][c] bf16, swizzled (32 KB)
    __shared__ __align__(16) unsigned short qkv[NO3 * 72];  // [row][col] bf16 (108 KB, pad 72)

    const int b    = blockIdx.y;
    const int l0   = blockIdx.x << 6;
    const int tid  = threadIdx.x;
    const int lane = tid & 63;
    const int w    = tid >> 6;          // wave id 0..7
    const int m    = lane & 15;
    const int g    = lane >> 4;

    // phase 0: stage x^T tile (coalesced global f32 read, transposed bf16 LDS write)
    {
        const int l = lane;
        #pragma unroll 8
        for (int p = 0; p < 32; ++p) {
            const int c = w + (p << 3);
            const float v = x[((size_t)(b * NC + c) << 14) + l0 + l];
            xT[(l * 256 + c) ^ ((l & 7) << 3)] = f2bf(v);
        }
    }
    __syncthreads();

    // phase 1: GEMM  qkv(768x64) = w_qkv(768x256, bf16) @ x(256x64)
    f32x4 acc[6][4];
    #pragma unroll
    for (int i = 0; i < 6; ++i) {
        #pragma unroll
        for (int j = 0; j < 4; ++j) acc[i][j] = f32x4{0.f, 0.f, 0.f, 0.f};
    }
    #pragma unroll
    for (int ks = 0; ks < 8; ++ks) {
        bf16x8 afr[6], bfr[4];
        #pragma unroll
        for (int rt = 0; rt < 6; ++rt)
            afr[rt] = ldfrag(wq + ((96 * w + 16 * rt + m) << 8) + (ks << 5) + (g << 3));
        #pragma unroll
        for (int ct = 0; ct < 4; ++ct) {
            const int col = (ct << 4) + m;
            bfr[ct] = ldfrag(xT + ((col * 256 + (ks << 5) + (g << 3)) ^ ((col & 7) << 3)));
        }
        #pragma unroll
        for (int rt = 0; rt < 6; ++rt) {
            #pragma unroll
            for (int ct = 0; ct < 4; ++ct)
                acc[rt][ct] = __builtin_amdgcn_mfma_f32_16x16x32_bf16(
                    afr[rt], bfr[ct], acc[rt][ct], 0, 0, 0);
        }
    }

    // phase 2: dump qkv tile to LDS (D-layout: col=lane&15, row=4*(lane>>4)+reg)
    #pragma unroll
    for (int rt = 0; rt < 6; ++rt) {
        #pragma unroll
        for (int ct = 0; ct < 4; ++ct) {
            #pragma unroll
            for (int r = 0; r < 4; ++r)
                qkv[(96 * w + 16 * rt + 4 * g + r) * 72 + (ct << 4) + m] =
                    f2bf(acc[rt][ct][r]);
        }
    }
    __syncthreads();

    // phase 3a: q softmax over d (32), * SCALE, store bf16 to q_ws
    {
        const int h = w, cc = lane;
        float vq[32];
        float s = 0.f;
        #pragma unroll
        for (int d = 0; d < 32; ++d) {
            const float f = __expf(bf2f(qkv[(32 * h + d) * 72 + cc]));
            vq[d] = f; s += f;
        }
        const float rs = Q_SCALE / s;
        unsigned short* qp = q_ws + ((size_t)(b * NC + 32 * h) << 14) + l0 + cc;
        #pragma unroll
        for (int d = 0; d < 32; ++d) qp[(size_t)d << 14] = f2bf(vq[d] * rs);
    }

    // phase 3b: k -> exp(k) in LDS (bf16), Z row partial sums
    {
        const int row = tid >> 1, half = tid & 1;
        unsigned short* kp = qkv + (NC + row) * 72 + (half << 5);
        float s = 0.f;
        #pragma unroll
        for (int j = 0; j < 32; ++j) {
            const unsigned short ub = f2bf(__expf(bf2f(kp[j])));
            kp[j] = ub;
            s += bf2f(ub);
        }
        s += __shfl_xor(s, 1);
        if (half == 0) atomicAdd(Zs + b * NC + row, s);
    }
    __syncthreads();

    // phase 3c: context partial: ctx[b,h,:,:] += ek(32xK=64) @ v^T, wave h
    {
        const int h = w;
        f32x4 ca[2][2];
        #pragma unroll
        for (int i = 0; i < 2; ++i) { ca[i][0] = f32x4{0.f,0.f,0.f,0.f}; ca[i][1] = f32x4{0.f,0.f,0.f,0.f}; }
        #pragma unroll
        for (int ks = 0; ks < 2; ++ks) {
            bf16x8 ea[2], vb[2];
            #pragma unroll
            for (int t = 0; t < 2; ++t) {
                ea[t] = ldfrag(qkv + (NC     + 32 * h + 16 * t + m) * 72 + (ks << 5) + (g << 3));
                vb[t] = ldfrag(qkv + (2 * NC + 32 * h + 16 * t + m) * 72 + (ks << 5) + (g << 3));
            }
            #pragma unroll
            for (int mt = 0; mt < 2; ++mt) {
                #pragma unroll
                for (int nt = 0; nt < 2; ++nt)
                    ca[mt][nt] = __builtin_amdgcn_mfma_f32_16x16x32_bf16(
                        ea[mt], vb[nt], ca[mt][nt], 0, 0, 0);
            }
        }
        float* cbase = ctx + ((b * NH + h) << 10);
        #pragma unroll
        for (int mt = 0; mt < 2; ++mt) {
            #pragma unroll
            for (int nt = 0; nt < 2; ++nt) {
                #pragma unroll
                for (int r = 0; r < 4; ++r)
                    atomicAdd(cbase + ((16 * mt + 4 * g + r) << 5) + (nt << 4) + m,
                              ca[mt][nt][r]);
            }
        }
    }
}

// ---------------------------------------------------------------- W2 build
// grid (NC, NB), 256 threads. W2[b,o,c=(h*32+d)] = sum_e w_out[o,h*32+e]*ctx[b,h,d,e]/Z[b,c]
__global__ __launch_bounds__(256) void k_w2(
    const float* __restrict__ w_out, const float* __restrict__ ctx,
    const float* __restrict__ Zs, unsigned short* __restrict__ W2)
{
    const int b = blockIdx.y, o = blockIdx.x, c = threadIdx.x;
    const int h = c >> 5, d = c & 31;
    const float zinv = 1.f / Zs[b * NC + c];
    const float* wrow = w_out + (o << 8) + (h << 5);
    const float* crow = ctx + ((b * NH + h) << 10) + (d << 5);
    float s = 0.f;
    #pragma unroll
    for (int e = 0; e < 32; ++e) s += wrow[e] * crow[e];
    W2[((size_t)(b * NC + o) << 8) + c] = f2bf(s * zinv);
}

// ---------------------------------------------------------------- pass 2
// grid (NL/128, NB), 512 threads. y = W2_b @ q_b + b_out ; sum/sumsq atomics.
__global__ __launch_bounds__(512) void k_out(
    const unsigned short* __restrict__ q_ws, const unsigned short* __restrict__ W2,
    const float* __restrict__ b_out, float* __restrict__ y, float* __restrict__ stats)
{
    __shared__ __align__(16) unsigned short qT[128 * 256];  // [l][c] bf16, swizzled (64 KB)
    __shared__ float red[16];

    const int b    = blockIdx.y;
    const int l0   = blockIdx.x << 7;
    const int tid  = threadIdx.x;
    const int lane = tid & 63, w = tid >> 6, m = lane & 15, g = lane >> 4;

    // stage q^T tile (bf16 bits copied, no conversion)
    {
        const int l = tid & 127, c0 = tid >> 7;
        const unsigned short* qp = q_ws + ((size_t)b << 22) + l0 + l;
        #pragma unroll 16
        for (int p = 0; p < 64; ++p) {
            const int c = c0 + (p << 2);
            qT[(l * 256 + c) ^ ((l & 7) << 3)] = qp[(size_t)c << 14];
        }
    }
    __syncthreads();

    const unsigned short* W2b = W2 + ((size_t)b << 16);
    f32x4 acc[2][8];
    #pragma unroll
    for (int i = 0; i < 2; ++i) {
        #pragma unroll
        for (int j = 0; j < 8; ++j) acc[i][j] = f32x4{0.f, 0.f, 0.f, 0.f};
    }
    #pragma unroll
    for (int ks = 0; ks < 8; ++ks) {
        bf16x8 afr[2], bfr[8];
        #pragma unroll
        for (int rt = 0; rt < 2; ++rt)
            afr[rt] = ldfrag(W2b + ((32 * w + 16 * rt + m) << 8) + (ks << 5) + (g << 3));
        #pragma unroll
        for (int ct = 0; ct < 8; ++ct) {
            const int col = (ct << 4) + m;
            bfr[ct] = ldfrag(qT + ((col * 256 + (ks << 5) + (g << 3)) ^ ((col & 7) << 3)));
        }
        #pragma unroll
        for (int rt = 0; rt < 2; ++rt) {
            #pragma unroll
            for (int ct = 0; ct < 8; ++ct)
                acc[rt][ct] = __builtin_amdgcn_mfma_f32_16x16x32_bf16(
                    afr[rt], bfr[ct], acc[rt][ct], 0, 0, 0);
        }
    }

    // epilogue: +b_out, write y, per-batch sum/sumsq
    float lsum = 0.f, lsq = 0.f;
    #pragma unroll
    for (int rt = 0; rt < 2; ++rt) {
        #pragma unroll
        for (int r = 0; r < 4; ++r) {
            const int row = 32 * w + 16 * rt + 4 * g + r;
            const float bo = b_out[row];
            float* yp = y + ((size_t)(b * NC + row) << 14) + l0 + m;
            #pragma unroll
            for (int ct = 0; ct < 8; ++ct) {
                const float v = acc[rt][ct][r] + bo;
                yp[ct << 4] = v;
                lsum += v; lsq += v * v;
            }
        }
    }
    #pragma unroll
    for (int off = 32; off > 0; off >>= 1) {
        lsum += __shfl_xor(lsum, off);
        lsq  += __shfl_xor(lsq,  off);
    }
    if (lane == 0) { red[w] = lsum; red[8 + w] = lsq; }
    __syncthreads();
    if (tid == 0) {
        float s = 0.f, s2 = 0.f;
        #pragma unroll
        for (int i = 0; i < 8; ++i) { s += red[i]; s2 += red[8 + i]; }
        atomicAdd(stats + b, s);
        atomicAdd(stats + 8 + b, s2);
    }
}

// ---------------------------------------------------------------- stats
__global__ __launch_bounds__(64) void k_stats(const float* __restrict__ stats,
                                              float* __restrict__ sc)
{
    const int b = threadIdx.x;
    if (b < 8) {
        const float invN = 1.f / 4194304.f;  // C*L
        const float mean = stats[b] * invN;
        const float var  = stats[8 + b] * invN - mean * mean;
        const float inv  = rsqrtf(var + GN_EPS);
        sc[b] = inv;
        sc[8 + b] = -mean * inv;
    }
}

// ---------------------------------------------------------------- normalize (in place)
__global__ __launch_bounds__(256) void k_norm(float* __restrict__ y,
    const float* __restrict__ sc, const float* __restrict__ gw, const float* __restrict__ gb)
{
    const size_t n4 = (size_t)NB * NC * NL / 4;
    for (size_t i = (size_t)blockIdx.x * 256 + threadIdx.x; i < n4;
         i += (size_t)gridDim.x * 256) {
        const size_t idx = i << 2;
        const int b = (int)(idx >> 22);
        const int c = (int)(idx >> 14) & 255;
        float4 v = ((float4*)y)[i];
        const float A  = sc[b] * gw[c];
        const float Bc = sc[8 + b] * gw[c] + gb[c];
        v.x = v.x * A + Bc; v.y = v.y * A + Bc;
        v.z = v.z * A + Bc; v.w = v.w * A + Bc;
        ((float4*)y)[i] = v;
    }
}

// ---------------------------------------------------------------- launcher
extern "C" void kernel_launch(void* const* d_in, const int* in_sizes, int n_in,
                              void* d_out, int out_size, void* d_ws, size_t ws_size,
                              hipStream_t stream)
{
    (void)in_sizes; (void)n_in; (void)out_size; (void)ws_size;
    const float* x     = (const float*)d_in[0];
    const float* w_qkv = (const float*)d_in[1];
    const float* w_out = (const float*)d_in[2];
    const float* b_out = (const float*)d_in[3];
    const float* gn_w  = (const float*)d_in[4];
    const float* gn_b  = (const float*)d_in[5];
    float* out = (float*)d_out;

    char* ws = (char*)d_ws;
    unsigned short* q_ws = (unsigned short*)(ws);              // 67,108,864 B
    unsigned short* wq   = (unsigned short*)(ws + 67108864);   //    393,216 B
    unsigned short* W2   = (unsigned short*)(ws + 67502080);   //  1,048,576 B
    float* ctx   = (float*)(ws + 68550656);                    //    262,144 B
    float* Zs    = (float*)(ws + 68812800);                    //      8,192 B
    float* stats = (float*)(ws + 68820992);                    //         64 B
    float* sc    = (float*)(ws + 68821056);                    //         64 B

    k_init <<<dim3(256),          dim3(256), 0, stream>>>(w_qkv, wq, ctx, Zs, stats);
    k_qkv  <<<dim3(NL / 64, NB),  dim3(512), 0, stream>>>(x, wq, q_ws, ctx, Zs);
    k_w2   <<<dim3(NC, NB),       dim3(256), 0, stream>>>(w_out, ctx, Zs, W2);
    k_out  <<<dim3(NL / 128, NB), dim3(512), 0, stream>>>(q_ws, W2, b_out, out, stats);
    k_stats<<<dim3(1),            dim3(64),  0, stream>>>(stats, sc);
    k_norm <<<dim3(2048),         dim3(256), 0, stream>>>(out, sc, gn_w, gn_b);
}

// Round 2
// 287.869 us; speedup vs baseline: 1.0057x; 1.0057x over previous
//
#include <hip/hip_runtime.h>
#include <hip/hip_bf16.h>
#include <cstdint>
#include <cstddef>

// LinearAttention fused pipeline for MI355X (gfx950).
//   x:(8,256,16384) f32, w_qkv:(768,256), w_out:(256,256), b_out:(256), gn_w/gn_b:(256)
// Pipeline:
//   k_init : w_qkv -> bf16, zero accumulators
//   k_qkv  : qkv = w_qkv@x (MFMA bf16), q-softmax(d)*SCALE -> q_ws (bf16),
//            ek=exp(k) ; ctx[b,h,d,e] += ek@v^T ; Z[b,c] += row-sums (atomics)
//   k_w2   : W2[b,o,hd] = sum_e w_out[o,he]*ctx[b,h,d,e]/Z[b,hd]  (bf16)
//   k_out  : y = W2_b @ q_b + b_out -> d_out (f32), per-batch sum/sumsq atomics
//   k_stats: mean/var -> scale/shift
//   k_norm : d_out = d_out*A[b,c] + B[b,c] in place (GroupNorm + gn_w/gn_b)

#define NB 8
#define NC 256
#define NL 16384
#define NH 8
#define ND 32
#define NO3 768

#define Q_SCALE 0.17677669529663687f
#define GN_EPS 1e-5f

using f32x4  = __attribute__((ext_vector_type(4))) float;
using bf16x8 = __attribute__((ext_vector_type(8))) __bf16;
using u32x4  = __attribute__((ext_vector_type(4))) unsigned int;

__device__ __forceinline__ float bf2f(unsigned short u) {
    union { unsigned int i; float f; } v; v.i = ((unsigned int)u) << 16; return v.f;
}
__device__ __forceinline__ unsigned short f2bf(float f) {
    union { float f; unsigned int i; } v; v.f = f;
    v.i += 0x7fffu + ((v.i >> 16) & 1u);   // RNE
    return (unsigned short)(v.i >> 16);
}
__device__ __forceinline__ bf16x8 ldfrag(const unsigned short* p) {
    return __builtin_bit_cast(bf16x8, *(const u32x4*)p);
}

// ---------------------------------------------------------------- init
__global__ __launch_bounds__(256) void k_init(
    const float* __restrict__ wqkv, unsigned short* __restrict__ wq,
    float* __restrict__ ctx, float* __restrict__ Zs, float* __restrict__ stats)
{
    const int i0 = blockIdx.x * 256 + threadIdx.x;
    const int stride = gridDim.x * 256;
    for (int i = i0; i < NO3 * NC; i += stride) wq[i] = f2bf(wqkv[i]);
    for (int i = i0; i < NB * NH * ND * ND; i += stride) ctx[i] = 0.f;
    for (int i = i0; i < NB * NC; i += stride) Zs[i] = 0.f;
    if (i0 < 16) stats[i0] = 0.f;
}

// ---------------------------------------------------------------- pass 1
// grid (NL/64, NB), 512 threads (8 waves). Per block: 768x64 qkv tile.
__global__ __launch_bounds__(512) void k_qkv(
    const float* __restrict__ x, const unsigned short* __restrict__ wq,
    unsigned short* __restrict__ q_ws, float* __restrict__ ctx, float* __restrict__ Zs)
{
    __shared__ __align__(16) unsigned short xT[64 * 256];   // [l][c] bf16, swizzled (32 KB)
    __shared__ __align__(16) unsigned short qkv[NO3 * 72];  // [row][col] bf16 (108 KB, pad 72)

    const int b    = blockIdx.y;
    const int l0   = blockIdx.x << 6;
    const int tid  = threadIdx.x;
    const int lane = tid & 63;
    const int w    = tid >> 6;          // wave id 0..7
    const int m    = lane & 15;
    const int g    = lane >> 4;

    // phase 0: stage x^T tile (coalesced global f32 read, transposed bf16 LDS write)
    {
        const int l = lane;
        #pragma unroll 8
        for (int p = 0; p < 32; ++p) {
            const int c = w + (p << 3);
            const float v = x[((size_t)(b * NC + c) << 14) + l0 + l];
            xT[(l * 256 + c) ^ ((l & 7) << 3)] = f2bf(v);
        }
    }
    __syncthreads();

    // phase 1: GEMM  qkv(768x64) = w_qkv(768x256, bf16) @ x(256x64)
    f32x4 acc[6][4];
    #pragma unroll
    for (int i = 0; i < 6; ++i) {
        #pragma unroll
        for (int j = 0; j < 4; ++j) acc[i][j] = f32x4{0.f, 0.f, 0.f, 0.f};
    }
    #pragma unroll
    for (int ks = 0; ks < 8; ++ks) {
        bf16x8 afr[6], bfr[4];
        #pragma unroll
        for (int rt = 0; rt < 6; ++rt)
            afr[rt] = ldfrag(wq + ((96 * w + 16 * rt + m) << 8) + (ks << 5) + (g << 3));
        #pragma unroll
        for (int ct = 0; ct < 4; ++ct) {
            const int col = (ct << 4) + m;
            bfr[ct] = ldfrag(xT + ((col * 256 + (ks << 5) + (g << 3)) ^ ((col & 7) << 3)));
        }
        #pragma unroll
        for (int rt = 0; rt < 6; ++rt) {
            #pragma unroll
            for (int ct = 0; ct < 4; ++ct)
                acc[rt][ct] = __builtin_amdgcn_mfma_f32_16x16x32_bf16(
                    afr[rt], bfr[ct], acc[rt][ct], 0, 0, 0);
        }
    }

    // phase 2: dump qkv tile to LDS (D-layout: col=lane&15, row=4*(lane>>4)+reg)
    #pragma unroll
    for (int rt = 0; rt < 6; ++rt) {
        #pragma unroll
        for (int ct = 0; ct < 4; ++ct) {
            #pragma unroll
            for (int r = 0; r < 4; ++r)
                qkv[(96 * w + 16 * rt + 4 * g + r) * 72 + (ct << 4) + m] =
                    f2bf(acc[rt][ct][r]);
        }
    }
    __syncthreads();

    // phase 3a: q softmax over d (32), * SCALE, store bf16 to q_ws
    {
        const int h = w, cc = lane;
        float vq[32];
        float s = 0.f;
        #pragma unroll
        for (int d = 0; d < 32; ++d) {
            const float f = __expf(bf2f(qkv[(32 * h + d) * 72 + cc]));
            vq[d] = f; s += f;
        }
        const float rs = Q_SCALE / s;
        unsigned short* qp = q_ws + ((size_t)(b * NC + 32 * h) << 14) + l0 + cc;
        #pragma unroll
        for (int d = 0; d < 32; ++d) qp[(size_t)d << 14] = f2bf(vq[d] * rs);
    }

    // phase 3b: k -> exp(k) in LDS (bf16), Z row partial sums
    {
        const int row = tid >> 1, half = tid & 1;
        unsigned short* kp = qkv + (NC + row) * 72 + (half << 5);
        float s = 0.f;
        #pragma unroll
        for (int j = 0; j < 32; ++j) {
            const unsigned short ub = f2bf(__expf(bf2f(kp[j])));
            kp[j] = ub;
            s += bf2f(ub);
        }
        s += __shfl_xor(s, 1);
        if (half == 0) atomicAdd(Zs + b * NC + row, s);
    }
    __syncthreads();

    // phase 3c: context partial: ctx[b,h,:,:] += ek(32xK=64) @ v^T, wave h
    {
        const int h = w;
        f32x4 ca[2][2];
        #pragma unroll
        for (int i = 0; i < 2; ++i) { ca[i][0] = f32x4{0.f,0.f,0.f,0.f}; ca[i][1] = f32x4{0.f,0.f,0.f,0.f}; }
        #pragma unroll
        for (int ks = 0; ks < 2; ++ks) {
            bf16x8 ea[2], vb[2];
            #pragma unroll
            for (int t = 0; t < 2; ++t) {
                ea[t] = ldfrag(qkv + (NC     + 32 * h + 16 * t + m) * 72 + (ks << 5) + (g << 3));
                vb[t] = ldfrag(qkv + (2 * NC + 32 * h + 16 * t + m) * 72 + (ks << 5) + (g << 3));
            }
            #pragma unroll
            for (int mt = 0; mt < 2; ++mt) {
                #pragma unroll
                for (int nt = 0; nt < 2; ++nt)
                    ca[mt][nt] = __builtin_amdgcn_mfma_f32_16x16x32_bf16(
                        ea[mt], vb[nt], ca[mt][nt], 0, 0, 0);
            }
        }
        float* cbase = ctx + ((b * NH + h) << 10);
        #pragma unroll
        for (int mt = 0; mt < 2; ++mt) {
            #pragma unroll
            for (int nt = 0; nt < 2; ++nt) {
                #pragma unroll
                for (int r = 0; r < 4; ++r)
                    atomicAdd(cbase + ((16 * mt + 4 * g + r) << 5) + (nt << 4) + m,
                              ca[mt][nt][r]);
            }
        }
    }
}

// ---------------------------------------------------------------- W2 build
// grid (NC, NB), 256 threads. W2[b,o,c=(h*32+d)] = sum_e w_out[o,h*32+e]*ctx[b,h,d,e]/Z[b,c]
__global__ __launch_bounds__(256) void k_w2(
    const float* __restrict__ w_out, const float* __restrict__ ctx,
    const float* __restrict__ Zs, unsigned short* __restrict__ W2)
{
    const int b = blockIdx.y, o = blockIdx.x, c = threadIdx.x;
    const int h = c >> 5, d = c & 31;
    const float zinv = 1.f / Zs[b * NC + c];
    const float* wrow = w_out + (o << 8) + (h << 5);
    const float* crow = ctx + ((b * NH + h) << 10) + (d << 5);
    float s = 0.f;
    #pragma unroll
    for (int e = 0; e < 32; ++e) s += wrow[e] * crow[e];
    W2[((size_t)(b * NC + o) << 8) + c] = f2bf(s * zinv);
}

// ---------------------------------------------------------------- pass 2
// grid (NL/128, NB), 512 threads. y = W2_b @ q_b + b_out ; sum/sumsq atomics.
__global__ __launch_bounds__(512) void k_out(
    const unsigned short* __restrict__ q_ws, const unsigned short* __restrict__ W2,
    const float* __restrict__ b_out, float* __restrict__ y, float* __restrict__ stats)
{
    __shared__ __align__(16) unsigned short qT[128 * 256];  // [l][c] bf16, swizzled (64 KB)
    __shared__ float red[16];

    const int b    = blockIdx.y;
    const int l0   = blockIdx.x << 7;
    const int tid  = threadIdx.x;
    const int lane = tid & 63, w = tid >> 6, m = lane & 15, g = lane >> 4;

    // stage q^T tile (bf16 bits copied, no conversion)
    {
        const int l = tid & 127, c0 = tid >> 7;
        const unsigned short* qp = q_ws + ((size_t)b << 22) + l0 + l;
        #pragma unroll 16
        for (int p = 0; p < 64; ++p) {
            const int c = c0 + (p << 2);
            qT[(l * 256 + c) ^ ((l & 7) << 3)] = qp[(size_t)c << 14];
        }
    }
    __syncthreads();

    const unsigned short* W2b = W2 + ((size_t)b << 16);
    f32x4 acc[2][8];
    #pragma unroll
    for (int i = 0; i < 2; ++i) {
        #pragma unroll
        for (int j = 0; j < 8; ++j) acc[i][j] = f32x4{0.f, 0.f, 0.f, 0.f};
    }
    #pragma unroll
    for (int ks = 0; ks < 8; ++ks) {
        bf16x8 afr[2], bfr[8];
        #pragma unroll
        for (int rt = 0; rt < 2; ++rt)
            afr[rt] = ldfrag(W2b + ((32 * w + 16 * rt + m) << 8) + (ks << 5) + (g << 3));
        #pragma unroll
        for (int ct = 0; ct < 8; ++ct) {
            const int col = (ct << 4) + m;
            bfr[ct] = ldfrag(qT + ((col * 256 + (ks << 5) + (g << 3)) ^ ((col & 7) << 3)));
        }
        #pragma unroll
        for (int rt = 0; rt < 2; ++rt) {
            #pragma unroll
            for (int ct = 0; ct < 8; ++ct)
                acc[rt][ct] = __builtin_amdgcn_mfma_f32_16x16x32_bf16(
                    afr[rt], bfr[ct], acc[rt][ct], 0, 0, 0);
        }
    }

    // epilogue: +b_out, write y, per-batch sum/sumsq
    float lsum = 0.f, lsq = 0.f;
    #pragma unroll
    for (int rt = 0; rt < 2; ++rt) {
        #pragma unroll
        for (int r = 0; r < 4; ++r) {
            const int row = 32 * w + 16 * rt + 4 * g + r;
            const float bo = b_out[row];
            float* yp = y + ((size_t)(b * NC + row) << 14) + l0 + m;
            #pragma unroll
            for (int ct = 0; ct < 8; ++ct) {
                const float v = acc[rt][ct][r] + bo;
                yp[ct << 4] = v;
                lsum += v; lsq += v * v;
            }
        }
    }
    #pragma unroll
    for (int off = 32; off > 0; off >>= 1) {
        lsum += __shfl_xor(lsum, off);
        lsq  += __shfl_xor(lsq,  off);
    }
    if (lane == 0) { red[w] = lsum; red[8 + w] = lsq; }
    __syncthreads();
    if (tid == 0) {
        float s = 0.f, s2 = 0.f;
        #pragma unroll
        for (int i = 0; i < 8; ++i) { s += red[i]; s2 += red[8 + i]; }
        atomicAdd(stats + b, s);
        atomicAdd(stats + 8 + b, s2);
    }
}

// ---------------------------------------------------------------- stats
__global__ __launch_bounds__(64) void k_stats(const float* __restrict__ stats,
                                              float* __restrict__ sc)
{
    const int b = threadIdx.x;
    if (b < 8) {
        const float invN = 1.f / 4194304.f;  // C*L
        const float mean = stats[b] * invN;
        const float var  = stats[8 + b] * invN - mean * mean;
        const float inv  = rsqrtf(var + GN_EPS);
        sc[b] = inv;
        sc[8 + b] = -mean * inv;
    }
}

// ---------------------------------------------------------------- normalize (in place)
__global__ __launch_bounds__(256) void k_norm(float* __restrict__ y,
    const float* __restrict__ sc, const float* __restrict__ gw, const float* __restrict__ gb)
{
    const size_t n4 = (size_t)NB * NC * NL / 4;
    for (size_t i = (size_t)blockIdx.x * 256 + threadIdx.x; i < n4;
         i += (size_t)gridDim.x * 256) {
        const size_t idx = i << 2;
        const int b = (int)(idx >> 22);
        const int c = (int)(idx >> 14) & 255;
        float4 v = ((float4*)y)[i];
        const float A  = sc[b] * gw[c];
        const float Bc = sc[8 + b] * gw[c] + gb[c];
        v.x = v.x * A + Bc; v.y = v.y * A + Bc;
        v.z = v.z * A + Bc; v.w = v.w * A + Bc;
        ((float4*)y)[i] = v;
    }
}

// ---------------------------------------------------------------- launcher
extern "C" void kernel_launch(void* const* d_in, const int* in_sizes, int n_in,
                              void* d_out, int out_size, void* d_ws, size_t ws_size,
                              hipStream_t stream)
{
    (void)in_sizes; (void)n_in; (void)out_size; (void)ws_size;
    const float* x     = (const float*)d_in[0];
    const float* w_qkv = (const float*)d_in[1];
    const float* w_out = (const float*)d_in[2];
    const float* b_out = (const float*)d_in[3];
    const float* gn_w  = (const float*)d_in[4];
    const float* gn_b  = (const float*)d_in[5];
    float* out = (float*)d_out;

    char* ws = (char*)d_ws;
    unsigned short* q_ws = (unsigned short*)(ws);              // 67,108,864 B
    unsigned short* wq   = (unsigned short*)(ws + 67108864);   //    393,216 B
    unsigned short* W2   = (unsigned short*)(ws + 67502080);   //  1,048,576 B
    float* ctx   = (float*)(ws + 68550656);                    //    262,144 B
    float* Zs    = (float*)(ws + 68812800);                    //      8,192 B
    float* stats = (float*)(ws + 68820992);                    //         64 B
    float* sc    = (float*)(ws + 68821056);                    //         64 B

    k_init <<<dim3(256),          dim3(256), 0, stream>>>(w_qkv, wq, ctx, Zs, stats);
    k_qkv  <<<dim3(NL / 64, NB),  dim3(512), 0, stream>>>(x, wq, q_ws, ctx, Zs);
    k_w2   <<<dim3(NC, NB),       dim3(256), 0, stream>>>(w_out, ctx, Zs, W2);
    k_out  <<<dim3(NL / 128, NB), dim3(512), 0, stream>>>(q_ws, W2, b_out, out, stats);
    k_stats<<<dim3(1),            dim3(64),  0, stream>>>(stats, sc);
    k_norm <<<dim3(2048),         dim3(256), 0, stream>>>(out, sc, gn_w, gn_b);
}